// Round 1
// baseline (3902.096 us; speedup 1.0000x reference)
//
#include <hip/hip_runtime.h>
#include <math.h>

// AcousticRadianceTransfer — time-domain reformulation.
// Key identity: rfft-domain multiply by D(d) == circular shift by d samples
// + scalar decay gamma^(d/SR). All ops linear -> run everything in time
// domain (real f32), fold detection-weight contraction into each bounce,
// single tiny output of 1600 floats. No FFT needed.

static constexpr float kSR = 16000.0f;
static constexpr int   kL = 1600;
static constexpr int   kLC = 400;          // float4 chunks per row
static constexpr int   kNRad = 24000;
static constexpr int   kNNZ = 480000;
static constexpr int   kNPatch = 256;
static constexpr int   kNBounce = 8;
static constexpr int   kNWG = 3000;        // workgroups in main kernels
static constexpr int   kRowsPerWG = 8;     // kNWG * kRowsPerWG == kNRad
static constexpr float kLogGamma = -6.907755278982137f; // ln(0.001)

__device__ __forceinline__ void fma4(float4& a, float v, const float4 b) {
    a.x = fmaf(v, b.x, a.x); a.y = fmaf(v, b.y, a.y);
    a.z = fmaf(v, b.z, a.z); a.w = fmaf(v, b.w, a.w);
}

// write 4 consecutive (circularly) samples starting at n0, scaled by dec
__device__ __forceinline__ void store_shift4(float* __restrict__ rowp, int n0,
                                             float dec, const float4 a) {
    float vv0 = a.x, vv1 = a.y, vv2 = a.z, vv3 = a.w;
    int n;
    n = n0 + 0; if (n >= kL) n -= kL; rowp[n] = dec * vv0;
    n = n0 + 1; if (n >= kL) n -= kL; rowp[n] = dec * vv1;
    n = n0 + 2; if (n >= kL) n -= kL; rowp[n] = dec * vv2;
    n = n0 + 3; if (n >= kL) n -= kL; rowp[n] = dec * vv3;
}

// ---------------- CSR build ----------------

__global__ void k_hist(const int* __restrict__ row, int* __restrict__ cnt) {
    int e = blockIdx.x * 256 + threadIdx.x;
    if (e < kNNZ) atomicAdd(&cnt[row[e]], 1);
}

// single block: exclusive scan of cnt[kNRad] -> rowptr[0..kNRad], cursor=start
__global__ void k_scan(int* __restrict__ cnt_and_cursor, int* __restrict__ rowptr) {
    __shared__ int s[256];
    __shared__ int carry_s;
    int tid = threadIdx.x;
    if (tid == 0) carry_s = 0;
    __syncthreads();
    for (int base = 0; base < kNRad; base += 256) {
        int i = base + tid;
        int v = (i < kNRad) ? cnt_and_cursor[i] : 0;
        s[tid] = v;
        __syncthreads();
        for (int off = 1; off < 256; off <<= 1) {
            int t = (tid >= off) ? s[tid - off] : 0;
            __syncthreads();
            s[tid] += t;
            __syncthreads();
        }
        int incl = s[tid];
        int c = carry_s;
        if (i < kNRad) {
            int ex = c + incl - v;
            rowptr[i] = ex;
            cnt_and_cursor[i] = ex;   // becomes scatter cursor
        }
        __syncthreads();
        if (tid == 255) carry_s = c + incl;
        __syncthreads();
    }
    if (tid == 0) rowptr[kNRad] = carry_s;
}

__global__ void k_scatter(const float* __restrict__ absorb,
                          const float* __restrict__ scat,
                          const float* __restrict__ basis,
                          const int* __restrict__ row,
                          const int* __restrict__ col,
                          const int* __restrict__ rid,
                          int* __restrict__ cursor,
                          int* __restrict__ ecol,
                          float* __restrict__ eval) {
    int e = blockIdx.x * 256 + threadIdx.x;
    if (e >= kNNZ) return;
    int rd = rid[e];
    float v = (scat[rd] * basis[e] + scat[kNPatch + rd] * basis[kNNZ + e]) * absorb[rd];
    int pos = atomicAdd(&cursor[row[e]], 1);
    ecol[pos] = col[e];
    eval[pos] = v;
}

__global__ void k_decay(const int* __restrict__ delay,
                        float* __restrict__ decay, int* __restrict__ dmod) {
    int i = blockIdx.x * 256 + threadIdx.x;
    if (i >= kNRad) return;
    int d = delay[i];
    decay[i] = expf(kLogGamma * (float)d / kSR);
    dmod[i] = d % kL;
}

// ---------------- init: curS0 = decay * shift(rad * fsm), y_part = w^T X0 ----

__global__ __launch_bounds__(256) void k_init(const float* __restrict__ rad,
                                              const float* __restrict__ w,
                                              const float* __restrict__ decay,
                                              const int* __restrict__ dmod,
                                              float* __restrict__ outS,
                                              float* __restrict__ y_part) {
    int wg = blockIdx.x, tid = threadIdx.x;
    bool has2 = tid < (kLC - 256);   // 144
    float4 f0, f1;
    {
        int m = 4 * tid;
        f0.x = expf(kLogGamma * (float)(m + 0) / kSR);
        f0.y = expf(kLogGamma * (float)(m + 1) / kSR);
        f0.z = expf(kLogGamma * (float)(m + 2) / kSR);
        f0.w = expf(kLogGamma * (float)(m + 3) / kSR);
        int m2 = 4 * (256 + tid);
        f1.x = expf(kLogGamma * (float)(m2 + 0) / kSR);
        f1.y = expf(kLogGamma * (float)(m2 + 1) / kSR);
        f1.z = expf(kLogGamma * (float)(m2 + 2) / kSR);
        f1.w = expf(kLogGamma * (float)(m2 + 3) / kSR);
    }
    float4 y0 = {0, 0, 0, 0}, y1 = {0, 0, 0, 0};
    for (int rr = 0; rr < kRowsPerWG; ++rr) {
        int r = wg * kRowsPerWG + rr;
        const float4* src = (const float4*)(rad + (size_t)r * kL);
        float wr = w[r];
        float dec = decay[r];
        int dd = dmod[r];
        float4 x0 = src[tid];
        x0.x *= f0.x; x0.y *= f0.y; x0.z *= f0.z; x0.w *= f0.w;
        fma4(y0, wr, x0);
        store_shift4(outS + (size_t)r * kL, 4 * tid + dd, dec, x0);
        if (has2) {
            float4 x1 = src[256 + tid];
            x1.x *= f1.x; x1.y *= f1.y; x1.z *= f1.z; x1.w *= f1.w;
            fma4(y1, wr, x1);
            store_shift4(outS + (size_t)r * kL, 4 * (256 + tid) + dd, dec, x1);
        }
    }
    float4* yp = (float4*)(y_part + (size_t)wg * kL);
    yp[tid] = y0;
    if (has2) yp[256 + tid] = y1;
}

// ---------------- one bounce: out = A * inS (aligned gathers), y += w^T out,
//                  stored shifted+decayed for the next bounce ----------------

__global__ __launch_bounds__(256) void k_bounce(const float* __restrict__ inS,
                                                float* __restrict__ outS,
                                                float* __restrict__ y_part,
                                                const int* __restrict__ ecol,
                                                const float* __restrict__ eval,
                                                const int* __restrict__ rowptr,
                                                const float* __restrict__ w,
                                                const float* __restrict__ decay,
                                                const int* __restrict__ dmod) {
    int wg = blockIdx.x, tid = threadIdx.x;
    bool has2 = tid < (kLC - 256);
    float4 y0 = {0, 0, 0, 0}, y1 = {0, 0, 0, 0};
    for (int rr = 0; rr < kRowsPerWG; ++rr) {
        int r = wg * kRowsPerWG + rr;
        int e0 = rowptr[r], e1 = rowptr[r + 1];
        float4 a0 = {0, 0, 0, 0}, a1 = {0, 0, 0, 0};
        for (int e = e0; e < e1; ++e) {
            float v = eval[e];
            int c = ecol[e];
            const float4* src = (const float4*)(inS + (size_t)c * kL);
            fma4(a0, v, src[tid]);
            if (has2) fma4(a1, v, src[256 + tid]);
        }
        float wr = w[r];
        fma4(y0, wr, a0);
        if (has2) fma4(y1, wr, a1);
        float dec = decay[r];
        int dd = dmod[r];
        store_shift4(outS + (size_t)r * kL, 4 * tid + dd, dec, a0);
        if (has2) store_shift4(outS + (size_t)r * kL, 4 * (256 + tid) + dd, dec, a1);
    }
    float4* yp = (float4*)(y_part + (size_t)wg * kL);
    float4 p0 = yp[tid];
    p0.x += y0.x; p0.y += y0.y; p0.z += y0.z; p0.w += y0.w;
    yp[tid] = p0;
    if (has2) {
        float4 p1 = yp[256 + tid];
        p1.x += y1.x; p1.y += y1.y; p1.z += y1.z; p1.w += y1.w;
        yp[256 + tid] = p1;
    }
}

// ---------------- finish: out[n] = (sum_wg y_part) * exp(env) / fsm ---------

__global__ void k_finish(const float* __restrict__ y_part,
                         const float* __restrict__ env,
                         float* __restrict__ out) {
    int n = blockIdx.x * 256 + threadIdx.x;
    if (n >= kL) return;
    float s = 0.0f;
    for (int wgi = 0; wgi < kNWG; ++wgi) s += y_part[(size_t)wgi * kL + n];
    float t = (float)n / kSR;
    out[n] = s * expf(env[n] - kLogGamma * t);
}

extern "C" void kernel_launch(void* const* d_in, const int* in_sizes, int n_in,
                              void* d_out, int out_size, void* d_ws, size_t ws_size,
                              hipStream_t stream) {
    const float* absorb = (const float*)d_in[0];
    const float* scat   = (const float*)d_in[1];
    const float* rad    = (const float*)d_in[2];
    const float* w      = (const float*)d_in[3];
    const float* env    = (const float*)d_in[4];
    const float* basis  = (const float*)d_in[5];
    const int*   srow   = (const int*)d_in[6];
    const int*   scol   = (const int*)d_in[7];
    const int*   srid   = (const int*)d_in[8];
    const int*   delay  = (const int*)d_in[9];

    char* ws = (char*)d_ws;
    size_t off = 0;
    auto alloc = [&](size_t bytes) -> char* {
        char* p = ws + off;
        off += (bytes + 255) & ~size_t(255);
        return p;
    };
    float* curA   = (float*)alloc((size_t)kNRad * kL * 4);
    float* curB   = (float*)alloc((size_t)kNRad * kL * 4);
    float* ypart  = (float*)alloc((size_t)kNWG * kL * 4);
    int*   ecol   = (int*)alloc((size_t)kNNZ * 4);
    float* eval   = (float*)alloc((size_t)kNNZ * 4);
    int*   rowptr = (int*)alloc((size_t)(kNRad + 1) * 4);
    int*   cursor = (int*)alloc((size_t)kNRad * 4);
    float* decay  = (float*)alloc((size_t)kNRad * 4);
    int*   dmod   = (int*)alloc((size_t)kNRad * 4);
    (void)ws_size; (void)in_sizes; (void)n_in; (void)out_size; (void)scol;

    // CSR build
    hipMemsetAsync(cursor, 0, (size_t)kNRad * 4, stream);
    k_hist<<<(kNNZ + 255) / 256, 256, 0, stream>>>(srow, cursor);
    k_scan<<<1, 256, 0, stream>>>(cursor, rowptr);
    k_decay<<<(kNRad + 255) / 256, 256, 0, stream>>>(delay, decay, dmod);
    k_scatter<<<(kNNZ + 255) / 256, 256, 0, stream>>>(absorb, scat, basis, srow,
                                                      scol, srid, cursor, ecol, eval);

    // init
    k_init<<<kNWG, 256, 0, stream>>>(rad, w, decay, dmod, curA, ypart);

    // 8 bounces, ping-pong
    const float* in = curA;
    float* outb = curB;
    for (int b = 0; b < kNBounce; ++b) {
        k_bounce<<<kNWG, 256, 0, stream>>>(in, outb, ypart, ecol, eval, rowptr,
                                           w, decay, dmod);
        const float* t = outb;
        outb = (float*)in;
        in = t;
    }

    // finish
    k_finish<<<(kL + 255) / 256, 256, 0, stream>>>(ypart, env, (float*)d_out);
}

// Round 2
// 2127.536 us; speedup vs baseline: 1.8341x; 1.8341x over previous
//
#include <hip/hip_runtime.h>
#include <math.h>

// AcousticRadianceTransfer — time-domain reformulation, bf16 state.
// rfft-multiply by D(d) == circular shift by d + scalar decay gamma^(d/SR).
// All ops linear -> run in time domain (real), fold detection-weight
// contraction into each bounce. Radiance ping-pong buffers stored as bf16
// (halves the L2-miss volume, which round-1 counters showed is the
// bottleneck: 1.5 GB L3-served fetch per bounce at ~3.3 TB/s). All
// accumulation in f32; only storage is rounded (RTN-even).

static constexpr float kSR = 16000.0f;
static constexpr int   kL = 1600;
static constexpr int   kSlices = 200;      // uint4 (8 bf16) slices per row
static constexpr int   kNRad = 24000;
static constexpr int   kNNZ = 480000;
static constexpr int   kNPatch = 256;
static constexpr int   kNBounce = 8;
static constexpr int   kNWG = 3000;
static constexpr int   kRowsPerWG = 8;     // kNWG * kRowsPerWG == kNRad
static constexpr float kLogGamma = -6.907755278982137f; // ln(0.001)

__device__ __forceinline__ unsigned short f2bf(float f) {
    unsigned int u = __float_as_uint(f);
    unsigned int r = u + 0x7fffu + ((u >> 16) & 1u);   // round-to-nearest-even
    return (unsigned short)(r >> 16);
}
__device__ __forceinline__ float bflo(unsigned int w) {
    return __uint_as_float(w << 16);
}
__device__ __forceinline__ float bfhi(unsigned int w) {
    return __uint_as_float(w & 0xffff0000u);
}

// ---------------- CSR build ----------------

__global__ void k_hist(const int* __restrict__ row, int* __restrict__ cnt) {
    int e = blockIdx.x * 256 + threadIdx.x;
    if (e < kNNZ) atomicAdd(&cnt[row[e]], 1);
}

__global__ void k_scan(int* __restrict__ cnt_and_cursor, int* __restrict__ rowptr) {
    __shared__ int s[256];
    __shared__ int carry_s;
    int tid = threadIdx.x;
    if (tid == 0) carry_s = 0;
    __syncthreads();
    for (int base = 0; base < kNRad; base += 256) {
        int i = base + tid;
        int v = (i < kNRad) ? cnt_and_cursor[i] : 0;
        s[tid] = v;
        __syncthreads();
        for (int off = 1; off < 256; off <<= 1) {
            int t = (tid >= off) ? s[tid - off] : 0;
            __syncthreads();
            s[tid] += t;
            __syncthreads();
        }
        int incl = s[tid];
        int c = carry_s;
        if (i < kNRad) {
            int ex = c + incl - v;
            rowptr[i] = ex;
            cnt_and_cursor[i] = ex;
        }
        __syncthreads();
        if (tid == 255) carry_s = c + incl;
        __syncthreads();
    }
    if (tid == 0) rowptr[kNRad] = carry_s;
}

__global__ void k_scatter(const float* __restrict__ absorb,
                          const float* __restrict__ scat,
                          const float* __restrict__ basis,
                          const int* __restrict__ row,
                          const int* __restrict__ col,
                          const int* __restrict__ rid,
                          int* __restrict__ cursor,
                          int2* __restrict__ epack) {
    int e = blockIdx.x * 256 + threadIdx.x;
    if (e >= kNNZ) return;
    int rd = rid[e];
    float v = (scat[rd] * basis[e] + scat[kNPatch + rd] * basis[kNNZ + e]) * absorb[rd];
    int pos = atomicAdd(&cursor[row[e]], 1);
    epack[pos] = make_int2(col[e], __float_as_int(v));
}

__global__ void k_decay(const int* __restrict__ delay,
                        float* __restrict__ decay, int* __restrict__ dmod) {
    int i = blockIdx.x * 256 + threadIdx.x;
    if (i >= kNRad) return;
    int d = delay[i];
    decay[i] = expf(kLogGamma * (float)d / kSR);
    dmod[i] = d % kL;
}

// ---------------- init: cur0 = bf16(decay * shift(rad * fsm)), y = w^T X0 ----

__global__ __launch_bounds__(256) void k_init(const float* __restrict__ rad,
                                              const float* __restrict__ w,
                                              const float* __restrict__ decay,
                                              const int* __restrict__ dmod,
                                              unsigned short* __restrict__ outS,
                                              float* __restrict__ y_part) {
    int wg = blockIdx.x, t = threadIdx.x;
    if (t >= kSlices) return;
    int m0 = 8 * t;
    float fsm[8];
#pragma unroll
    for (int i = 0; i < 8; ++i)
        fsm[i] = expf(kLogGamma * (float)(m0 + i) / kSR);
    float yacc[8] = {0, 0, 0, 0, 0, 0, 0, 0};
    for (int rr = 0; rr < kRowsPerWG; ++rr) {
        int r = wg * kRowsPerWG + rr;
        const float4* s4 = (const float4*)(rad + (size_t)r * kL);
        float4 a = s4[2 * t], b = s4[2 * t + 1];
        float v[8] = {a.x * fsm[0], a.y * fsm[1], a.z * fsm[2], a.w * fsm[3],
                      b.x * fsm[4], b.y * fsm[5], b.z * fsm[6], b.w * fsm[7]};
        float wr = w[r];
#pragma unroll
        for (int i = 0; i < 8; ++i) yacc[i] = fmaf(wr, v[i], yacc[i]);
        float dec = decay[r];
        int n0 = m0 + dmod[r];
        unsigned short* orow = outS + (size_t)r * kL;
#pragma unroll
        for (int i = 0; i < 8; ++i) {
            int n = n0 + i; if (n >= kL) n -= kL;
            orow[n] = f2bf(dec * v[i]);
        }
    }
    float* yp = y_part + (size_t)wg * kL + m0;
#pragma unroll
    for (int i = 0; i < 8; ++i) yp[i] = yacc[i];
}

// ---------------- one bounce ----------------

__global__ __launch_bounds__(256) void k_bounce(const unsigned short* __restrict__ inS,
                                                unsigned short* __restrict__ outS,
                                                float* __restrict__ y_part,
                                                const int2* __restrict__ epack,
                                                const int* __restrict__ rowptr,
                                                const float* __restrict__ w,
                                                const float* __restrict__ decay,
                                                const int* __restrict__ dmod) {
    int wg = blockIdx.x, t = threadIdx.x;
    if (t >= kSlices) return;
    int m0 = 8 * t;
    float yacc[8] = {0, 0, 0, 0, 0, 0, 0, 0};
    for (int rr = 0; rr < kRowsPerWG; ++rr) {
        int r = wg * kRowsPerWG + rr;
        int e0 = rowptr[r], e1 = rowptr[r + 1];
        float acc[8] = {0, 0, 0, 0, 0, 0, 0, 0};
        for (int e = e0; e < e1; ++e) {
            int2 p = epack[e];
            float v = __int_as_float(p.y);
            const uint4* src = (const uint4*)(inS + (size_t)p.x * kL);
            uint4 q = src[t];
            acc[0] = fmaf(v, bflo(q.x), acc[0]);
            acc[1] = fmaf(v, bfhi(q.x), acc[1]);
            acc[2] = fmaf(v, bflo(q.y), acc[2]);
            acc[3] = fmaf(v, bfhi(q.y), acc[3]);
            acc[4] = fmaf(v, bflo(q.z), acc[4]);
            acc[5] = fmaf(v, bfhi(q.z), acc[5]);
            acc[6] = fmaf(v, bflo(q.w), acc[6]);
            acc[7] = fmaf(v, bfhi(q.w), acc[7]);
        }
        float wr = w[r];
#pragma unroll
        for (int i = 0; i < 8; ++i) yacc[i] = fmaf(wr, acc[i], yacc[i]);
        float dec = decay[r];
        int n0 = m0 + dmod[r];
        unsigned short* orow = outS + (size_t)r * kL;
#pragma unroll
        for (int i = 0; i < 8; ++i) {
            int n = n0 + i; if (n >= kL) n -= kL;
            orow[n] = f2bf(dec * acc[i]);
        }
    }
    float* yp = y_part + (size_t)wg * kL + m0;
#pragma unroll
    for (int i = 0; i < 8; ++i) yp[i] += yacc[i];
}

// ---------------- finish: out[n] = (sum_wg y_part) * exp(env) / fsm ---------

__global__ void k_finish(const float* __restrict__ y_part,
                         const float* __restrict__ env,
                         float* __restrict__ out) {
    int n = blockIdx.x * 256 + threadIdx.x;
    if (n >= kL) return;
    float s = 0.0f;
    for (int wgi = 0; wgi < kNWG; ++wgi) s += y_part[(size_t)wgi * kL + n];
    float t = (float)n / kSR;
    out[n] = s * expf(env[n] - kLogGamma * t);
}

extern "C" void kernel_launch(void* const* d_in, const int* in_sizes, int n_in,
                              void* d_out, int out_size, void* d_ws, size_t ws_size,
                              hipStream_t stream) {
    const float* absorb = (const float*)d_in[0];
    const float* scat   = (const float*)d_in[1];
    const float* rad    = (const float*)d_in[2];
    const float* w      = (const float*)d_in[3];
    const float* env    = (const float*)d_in[4];
    const float* basis  = (const float*)d_in[5];
    const int*   srow   = (const int*)d_in[6];
    const int*   scol   = (const int*)d_in[7];
    const int*   srid   = (const int*)d_in[8];
    const int*   delay  = (const int*)d_in[9];

    char* ws = (char*)d_ws;
    size_t off = 0;
    auto alloc = [&](size_t bytes) -> char* {
        char* p = ws + off;
        off += (bytes + 255) & ~size_t(255);
        return p;
    };
    unsigned short* curA = (unsigned short*)alloc((size_t)kNRad * kL * 2);
    unsigned short* curB = (unsigned short*)alloc((size_t)kNRad * kL * 2);
    float* ypart  = (float*)alloc((size_t)kNWG * kL * 4);
    int2*  epack  = (int2*)alloc((size_t)kNNZ * 8);
    int*   rowptr = (int*)alloc((size_t)(kNRad + 1) * 4);
    int*   cursor = (int*)alloc((size_t)kNRad * 4);
    float* decay  = (float*)alloc((size_t)kNRad * 4);
    int*   dmod   = (int*)alloc((size_t)kNRad * 4);
    (void)ws_size; (void)in_sizes; (void)n_in; (void)out_size;

    // CSR build
    hipMemsetAsync(cursor, 0, (size_t)kNRad * 4, stream);
    k_hist<<<(kNNZ + 255) / 256, 256, 0, stream>>>(srow, cursor);
    k_scan<<<1, 256, 0, stream>>>(cursor, rowptr);
    k_decay<<<(kNRad + 255) / 256, 256, 0, stream>>>(delay, decay, dmod);
    k_scatter<<<(kNNZ + 255) / 256, 256, 0, stream>>>(absorb, scat, basis, srow,
                                                      scol, srid, cursor, epack);

    // init
    k_init<<<kNWG, 256, 0, stream>>>(rad, w, decay, dmod, curA, ypart);

    // 8 bounces, ping-pong
    const unsigned short* in = curA;
    unsigned short* outb = curB;
    for (int b = 0; b < kNBounce; ++b) {
        k_bounce<<<kNWG, 256, 0, stream>>>(in, outb, ypart, epack, rowptr,
                                           w, decay, dmod);
        const unsigned short* tmp = outb;
        outb = (unsigned short*)in;
        in = tmp;
    }

    // finish
    k_finish<<<(kL + 255) / 256, 256, 0, stream>>>(ypart, env, (float*)d_out);
}